// Round 4
// baseline (178.165 us; speedup 1.0000x reference)
//
#include <hip/hip_runtime.h>

#define IN_CH 128
#define HID 64
#define SCAN_CHUNK 1024   // elements scanned per block in scanA (256 thr x 4)

// branch-free f32 -> 2x bf16 pack, round-to-nearest-even, pure uint math
__device__ __forceinline__ unsigned int bf16pair(float a, float b) {
    unsigned int ua = __float_as_uint(a);
    unsigned int ub = __float_as_uint(b);
    ua = (ua + 0x7fffu + ((ua >> 16) & 1u)) >> 16;          // elem0 -> low 16
    ub = (ub + 0x7fffu + ((ub >> 16) & 1u)) & 0xffff0000u;  // elem1 -> high 16
    return ua | ub;
}

// ---------------------------------------------------------------------------
// Kernel 1: fused encoder GEMMs (+ deg zeroing for the CSR build).
//   y_rel[n][c] = bf16( sum_k x[n][k] * W_rel[k][c] )   (packed 2/word)
//   agg[n][c]   = sum_k x[n][k] * W_root[k][c] + b_rel[c]   (gather-init, f32)
// ---------------------------------------------------------------------------
__global__ __launch_bounds__(256) void graphmae_encode(
    const float* __restrict__ x, const float* __restrict__ W_rel,
    const float* __restrict__ b_rel, const float* __restrict__ W_root,
    unsigned int* __restrict__ y_relw,   // [N][32] words (2 bf16 each)
    float* __restrict__ agg, int* __restrict__ deg, int N)
{
    __shared__ float lw[64 * 128];   // k-half of [W_rel | W_root]
    __shared__ float xs[32 * 132];   // 32 x-rows, padded

    const int t  = threadIdx.x;
    const int tc = t & 31;
    const int tr = t >> 5;
    const int n0 = blockIdx.x * 32;

    // fold in: zero the degree array
    {
        const int z = blockIdx.x * 256 + t;
        if (z < N) deg[z] = 0;
    }

    #pragma unroll
    for (int p = 0; p < 4; ++p) {
        const int row = tr + p * 8;
        const int n   = n0 + row;
        float4 v = make_float4(0.f, 0.f, 0.f, 0.f);
        if (n < N) v = *(const float4*)(x + (size_t)n * IN_CH + tc * 4);
        *(float4*)(xs + row * 132 + tc * 4) = v;
    }

    float acc[4][4];
    #pragma unroll
    for (int i = 0; i < 4; ++i)
        #pragma unroll
        for (int j = 0; j < 4; ++j) acc[i][j] = 0.f;

    for (int kh = 0; kh < 2; ++kh) {
        __syncthreads();
        #pragma unroll
        for (int p = 0; p < 8; ++p) {
            const int idx  = t + p * 256;
            const int krow = idx >> 5;
            const int col4 = (idx & 31) * 4;
            float4 v;
            if (col4 < HID)
                v = *(const float4*)(W_rel  + (size_t)(kh * 64 + krow) * HID + col4);
            else
                v = *(const float4*)(W_root + (size_t)(kh * 64 + krow) * HID + (col4 - HID));
            *(float4*)(lw + idx * 4) = v;
        }
        __syncthreads();

        #pragma unroll 2
        for (int k = 0; k < 64; k += 4) {
            float4 w0 = *(const float4*)(lw + (k + 0) * 128 + tc * 4);
            float4 w1 = *(const float4*)(lw + (k + 1) * 128 + tc * 4);
            float4 w2 = *(const float4*)(lw + (k + 2) * 128 + tc * 4);
            float4 w3 = *(const float4*)(lw + (k + 3) * 128 + tc * 4);
            const float* w0f = (const float*)&w0;
            const float* w1f = (const float*)&w1;
            const float* w2f = (const float*)&w2;
            const float* w3f = (const float*)&w3;
            #pragma unroll
            for (int i = 0; i < 4; ++i) {
                const float4 xv = *(const float4*)(xs + (tr * 4 + i) * 132 + kh * 64 + k);
                const float* xf = (const float*)&xv;
                #pragma unroll
                for (int j = 0; j < 4; ++j) {
                    acc[i][j] += xf[0] * w0f[j];
                    acc[i][j] += xf[1] * w1f[j];
                    acc[i][j] += xf[2] * w2f[j];
                    acc[i][j] += xf[3] * w3f[j];
                }
            }
        }
    }

    const int c0 = (tc & 15) * 4;
    if (tc < 16) {
        #pragma unroll
        for (int i = 0; i < 4; ++i) {
            const int n = n0 + tr * 4 + i;
            if (n < N) {
                const unsigned int lo = bf16pair(acc[i][0], acc[i][1]);
                const unsigned int hi = bf16pair(acc[i][2], acc[i][3]);
                *(uint2*)(y_relw + (size_t)n * 32 + (c0 >> 1)) = make_uint2(lo, hi);
            }
        }
    } else {
        const float4 br = *(const float4*)(b_rel + c0);
        #pragma unroll
        for (int i = 0; i < 4; ++i) {
            const int n = n0 + tr * 4 + i;
            if (n < N)
                *(float4*)(agg + (size_t)n * HID + c0) =
                    make_float4(acc[i][0] + br.x, acc[i][1] + br.y,
                                acc[i][2] + br.z, acc[i][3] + br.w);
        }
    }
}

// ---------------------------------------------------------------------------
// CSR build: count -> scan(A,B,C) -> fill   (deg zeroed by encode)
// ---------------------------------------------------------------------------
__global__ __launch_bounds__(256) void csr_count(
    const int* __restrict__ ei, int* __restrict__ deg, int E)
{
    const int e = blockIdx.x * 256 + threadIdx.x;
    if (e < E) atomicAdd(&deg[ei[E + e]], 1);
}

__global__ __launch_bounds__(256) void csr_scanA(
    const int* __restrict__ deg, int* __restrict__ row_start,
    int* __restrict__ bsum, int N)
{
    __shared__ int sd[256];
    const int t    = threadIdx.x;
    const int base = blockIdx.x * SCAN_CHUNK + t * 4;

    int d[4];
    #pragma unroll
    for (int j = 0; j < 4; ++j) d[j] = (base + j < N) ? deg[base + j] : 0;
    const int tsum = d[0] + d[1] + d[2] + d[3];

    sd[t] = tsum;
    __syncthreads();
    for (int off = 1; off < 256; off <<= 1) {
        const int v = (t >= off) ? sd[t - off] : 0;
        __syncthreads();
        sd[t] += v;
        __syncthreads();
    }
    int run = sd[t] - tsum;
    #pragma unroll
    for (int j = 0; j < 4; ++j) {
        if (base + j < N) row_start[base + j] = run;
        run += d[j];
    }
    if (t == 255) bsum[blockIdx.x] = sd[255];
}

// wave-parallel exclusive scan of block sums (NB <= 64) + row_start[N] = E
__global__ void csr_scanB(int* __restrict__ bsum, int* __restrict__ row_start,
                          int NB, int N, int E)
{
    const int lane = threadIdx.x & 63;
    int v = (lane < NB) ? bsum[lane] : 0;
    int x = v;
    #pragma unroll
    for (int off = 1; off < 64; off <<= 1) {
        const int u = __shfl(x, lane - off);
        if (lane >= off) x += u;
    }
    if (lane < NB) bsum[lane] = x - v;   // exclusive
    if (lane == 0) row_start[N] = E;
}

__global__ __launch_bounds__(256) void csr_scanC(
    int* __restrict__ row_start, int* __restrict__ cursor,
    const int* __restrict__ bsum, int N)
{
    const int i = blockIdx.x * 256 + threadIdx.x;
    if (i < N) {
        const int v = row_start[i] + bsum[i / SCAN_CHUNK];
        row_start[i] = v;
        cursor[i] = v;
    }
}

__global__ __launch_bounds__(256) void csr_fill(
    const int* __restrict__ ei, int* __restrict__ cursor,
    int* __restrict__ col, int E)
{
    const int e = blockIdx.x * 256 + threadIdx.x;
    if (e < E) {
        const int s = ei[e];
        const int d = ei[E + e];
        const int p = atomicAdd(&cursor[d], 1);
        col[p] = s;
    }
}

// ---------------------------------------------------------------------------
// Kernel 2: fused gather + decoder.
// GATHER phase is decomposed by TRUE wave64: wid = t>>6 (4 waves), each wave
// owns 8 hs rows; within a wave: 4 edge-slots (lane>>4) x 16 col-lanes
// (lane&15), shfl_xor(16|32) reduces edge slots WITHIN one node's wave.
// GEMM phase keeps per-thread 32-group tiling (no cross-lane ops).
// ---------------------------------------------------------------------------
__global__ __launch_bounds__(256) void graphmae_gather_decode(
    const int* __restrict__ row_start, const int* __restrict__ col,
    const unsigned int* __restrict__ y_relw, const float* __restrict__ agg,
    const float* __restrict__ W_dec, const float* __restrict__ b_dec,
    float* __restrict__ out, int N)
{
    __shared__ float wd[64 * 128];   // W_dec
    __shared__ float hs[32 * 68];    // relu(h) tile, padded

    const int t  = threadIdx.x;
    const int n0 = blockIdx.x * 32;

    // stage W_dec (consumed after the __syncthreads below)
    #pragma unroll
    for (int p = 0; p < 8; ++p) {
        const int idx = t + p * 256;
        *(float4*)(wd + idx * 4) = *(const float4*)(W_dec + (size_t)idx * 4);
    }

    // ---- gather phase ----
    const int wid  = t >> 6;      // true wave id 0..3
    const int lane = t & 63;
    const int es   = lane >> 4;   // edge slot 0..3
    const int cl   = lane & 15;   // col group: floats cl*4 .. cl*4+3
    #pragma unroll
    for (int j = 0; j < 8; ++j) {
        const int row = wid * 8 + j;
        const int n   = n0 + row;
        if (n >= N) continue;     // uniform across the wave
        const int beg = row_start[n];
        const int end = row_start[n + 1];

        float4 acc = make_float4(0.f, 0.f, 0.f, 0.f);
        for (int e = beg + es; e < end; e += 4) {
            const int s = col[e];
            const uint2 v = *(const uint2*)(y_relw + (size_t)s * 32 + cl * 2);
            acc.x += __uint_as_float(v.x << 16);
            acc.y += __uint_as_float(v.x & 0xffff0000u);
            acc.z += __uint_as_float(v.y << 16);
            acc.w += __uint_as_float(v.y & 0xffff0000u);
        }
        // reduce the 4 edge slots (lane bits 4,5) — within ONE node's wave
        acc.x += __shfl_xor(acc.x, 16); acc.y += __shfl_xor(acc.y, 16);
        acc.z += __shfl_xor(acc.z, 16); acc.w += __shfl_xor(acc.w, 16);
        acc.x += __shfl_xor(acc.x, 32); acc.y += __shfl_xor(acc.y, 32);
        acc.z += __shfl_xor(acc.z, 32); acc.w += __shfl_xor(acc.w, 32);

        if (es == 0) {
            const float4 a0 = *(const float4*)(agg + (size_t)n * HID + cl * 4);
            float4 h;
            h.x = fmaxf(a0.x + acc.x, 0.f);
            h.y = fmaxf(a0.y + acc.y, 0.f);
            h.z = fmaxf(a0.z + acc.z, 0.f);
            h.w = fmaxf(a0.w + acc.w, 0.f);
            *(float4*)(hs + row * 68 + cl * 4) = h;
        }
    }
    __syncthreads();

    // ---- GEMM: out[n] = hs[n] @ W_dec + b_dec ----
    const int tc = t & 31;
    const int tr = t >> 5;

    float acc[4][4];
    #pragma unroll
    for (int i = 0; i < 4; ++i)
        #pragma unroll
        for (int j = 0; j < 4; ++j) acc[i][j] = 0.f;

    const int c0 = tc * 4;
    #pragma unroll 2
    for (int k = 0; k < 64; k += 4) {
        float4 w0 = *(const float4*)(wd + (k + 0) * 128 + c0);
        float4 w1 = *(const float4*)(wd + (k + 1) * 128 + c0);
        float4 w2 = *(const float4*)(wd + (k + 2) * 128 + c0);
        float4 w3 = *(const float4*)(wd + (k + 3) * 128 + c0);
        const float* w0f = (const float*)&w0;
        const float* w1f = (const float*)&w1;
        const float* w2f = (const float*)&w2;
        const float* w3f = (const float*)&w3;
        #pragma unroll
        for (int i = 0; i < 4; ++i) {
            const float4 hv = *(const float4*)(hs + (tr * 4 + i) * 68 + k);
            const float* hf = (const float*)&hv;
            #pragma unroll
            for (int j = 0; j < 4; ++j) {
                acc[i][j] += hf[0] * w0f[j];
                acc[i][j] += hf[1] * w1f[j];
                acc[i][j] += hf[2] * w2f[j];
                acc[i][j] += hf[3] * w3f[j];
            }
        }
    }

    const float4 bd = *(const float4*)(b_dec + c0);
    #pragma unroll
    for (int i = 0; i < 4; ++i) {
        const int n = n0 + tr * 4 + i;
        if (n < N)
            *(float4*)(out + (size_t)n * IN_CH + c0) =
                make_float4(acc[i][0] + bd.x, acc[i][1] + bd.y,
                            acc[i][2] + bd.z, acc[i][3] + bd.w);
    }
}

// ---------------------------------------------------------------------------
extern "C" void kernel_launch(void* const* d_in, const int* in_sizes, int n_in,
                              void* d_out, int out_size, void* d_ws, size_t ws_size,
                              hipStream_t stream)
{
    const float* x      = (const float*)d_in[0];
    const int*   ei     = (const int*)  d_in[1];   // [2][E] int32
    const float* W_rel  = (const float*)d_in[2];
    const float* b_rel  = (const float*)d_in[3];
    const float* W_root = (const float*)d_in[4];
    const float* W_dec  = (const float*)d_in[5];
    const float* b_dec  = (const float*)d_in[6];
    float* out = (float*)d_out;

    const int N = in_sizes[0] / IN_CH;
    const int E = in_sizes[1] / 2;

    unsigned int* y_relw = (unsigned int*)d_ws;               // [N][32] words (bf16x2)
    float* agg       = (float*)(y_relw + (size_t)N * 32);     // [N][64] f32
    int*   row_start = (int*)(agg + (size_t)N * HID);         // [N+1]
    int*   cursor    = row_start + (N + 1);                   // [N]
    int*   deg       = cursor + N;                            // [N]
    int*   col       = deg + N;                               // [E]
    int*   bsum      = col + E;                               // [NB]

    const int nblk = (N + 31) / 32;
    const int nthr = (N + 255) / 256;
    const int ethr = (E + 255) / 256;
    const int NB   = (N + SCAN_CHUNK - 1) / SCAN_CHUNK;

    graphmae_encode<<<nblk, 256, 0, stream>>>(x, W_rel, b_rel, W_root,
                                              y_relw, agg, deg, N);
    csr_count<<<ethr, 256, 0, stream>>>(ei, deg, E);
    csr_scanA<<<NB,   256, 0, stream>>>(deg, row_start, bsum, N);
    csr_scanB<<<1,     64, 0, stream>>>(bsum, row_start, NB, N, E);
    csr_scanC<<<nthr, 256, 0, stream>>>(row_start, cursor, bsum, N);
    csr_fill <<<ethr, 256, 0, stream>>>(ei, cursor, col, E);
    graphmae_gather_decode<<<nblk, 256, 0, stream>>>(row_start, col, y_relw, agg,
                                                     W_dec, b_dec, out, N);
}

// Round 5
// 143.947 us; speedup vs baseline: 1.2377x; 1.2377x over previous
//
#include <hip/hip_runtime.h>

#define IN_CH 128
#define HID 64
#define SCAN_CHUNK 1024   // elements scanned per block in scanA (256 thr x 4)

// branch-free f32 -> 2x bf16 pack, round-to-nearest-even, pure uint math
__device__ __forceinline__ unsigned int bf16pair(float a, float b) {
    unsigned int ua = __float_as_uint(a);
    unsigned int ub = __float_as_uint(b);
    ua = (ua + 0x7fffu + ((ua >> 16) & 1u)) >> 16;          // elem0 -> low 16
    ub = (ub + 0x7fffu + ((ub >> 16) & 1u)) & 0xffff0000u;  // elem1 -> high 16
    return ua | ub;
}

// ---------------------------------------------------------------------------
// Kernel 1: fused encoder GEMMs (+ deg zeroing for the CSR build).
//   y_rel[n][c] = bf16( sum_k x[n][k] * W_rel[k][c] )   (packed 2/word)
//   agg[n][c]   = sum_k x[n][k] * W_root[k][c] + b_rel[c]   (gather-init, f32)
// ---------------------------------------------------------------------------
__global__ __launch_bounds__(256) void graphmae_encode(
    const float* __restrict__ x, const float* __restrict__ W_rel,
    const float* __restrict__ b_rel, const float* __restrict__ W_root,
    unsigned int* __restrict__ y_relw,   // [N][32] words (2 bf16 each)
    float* __restrict__ agg, int* __restrict__ deg, int N)
{
    __shared__ float lw[64 * 128];   // k-half of [W_rel | W_root]
    __shared__ float xs[32 * 132];   // 32 x-rows, padded

    const int t  = threadIdx.x;
    const int tc = t & 31;
    const int tr = t >> 5;
    const int n0 = blockIdx.x * 32;

    // fold in: zero the degree array
    {
        const int z = blockIdx.x * 256 + t;
        if (z < N) deg[z] = 0;
    }

    #pragma unroll
    for (int p = 0; p < 4; ++p) {
        const int row = tr + p * 8;
        const int n   = n0 + row;
        float4 v = make_float4(0.f, 0.f, 0.f, 0.f);
        if (n < N) v = *(const float4*)(x + (size_t)n * IN_CH + tc * 4);
        *(float4*)(xs + row * 132 + tc * 4) = v;
    }

    float acc[4][4];
    #pragma unroll
    for (int i = 0; i < 4; ++i)
        #pragma unroll
        for (int j = 0; j < 4; ++j) acc[i][j] = 0.f;

    for (int kh = 0; kh < 2; ++kh) {
        __syncthreads();
        #pragma unroll
        for (int p = 0; p < 8; ++p) {
            const int idx  = t + p * 256;
            const int krow = idx >> 5;
            const int col4 = (idx & 31) * 4;
            float4 v;
            if (col4 < HID)
                v = *(const float4*)(W_rel  + (size_t)(kh * 64 + krow) * HID + col4);
            else
                v = *(const float4*)(W_root + (size_t)(kh * 64 + krow) * HID + (col4 - HID));
            *(float4*)(lw + idx * 4) = v;
        }
        __syncthreads();

        #pragma unroll 2
        for (int k = 0; k < 64; k += 4) {
            float4 w0 = *(const float4*)(lw + (k + 0) * 128 + tc * 4);
            float4 w1 = *(const float4*)(lw + (k + 1) * 128 + tc * 4);
            float4 w2 = *(const float4*)(lw + (k + 2) * 128 + tc * 4);
            float4 w3 = *(const float4*)(lw + (k + 3) * 128 + tc * 4);
            const float* w0f = (const float*)&w0;
            const float* w1f = (const float*)&w1;
            const float* w2f = (const float*)&w2;
            const float* w3f = (const float*)&w3;
            #pragma unroll
            for (int i = 0; i < 4; ++i) {
                const float4 xv = *(const float4*)(xs + (tr * 4 + i) * 132 + kh * 64 + k);
                const float* xf = (const float*)&xv;
                #pragma unroll
                for (int j = 0; j < 4; ++j) {
                    acc[i][j] += xf[0] * w0f[j];
                    acc[i][j] += xf[1] * w1f[j];
                    acc[i][j] += xf[2] * w2f[j];
                    acc[i][j] += xf[3] * w3f[j];
                }
            }
        }
    }

    const int c0 = (tc & 15) * 4;
    if (tc < 16) {
        #pragma unroll
        for (int i = 0; i < 4; ++i) {
            const int n = n0 + tr * 4 + i;
            if (n < N) {
                const unsigned int lo = bf16pair(acc[i][0], acc[i][1]);
                const unsigned int hi = bf16pair(acc[i][2], acc[i][3]);
                *(uint2*)(y_relw + (size_t)n * 32 + (c0 >> 1)) = make_uint2(lo, hi);
            }
        }
    } else {
        const float4 br = *(const float4*)(b_rel + c0);
        #pragma unroll
        for (int i = 0; i < 4; ++i) {
            const int n = n0 + tr * 4 + i;
            if (n < N)
                *(float4*)(agg + (size_t)n * HID + c0) =
                    make_float4(acc[i][0] + br.x, acc[i][1] + br.y,
                                acc[i][2] + br.z, acc[i][3] + br.w);
        }
    }
}

// ---------------------------------------------------------------------------
// CSR build: count -> scan(A,B,C) -> fill   (deg zeroed by encode)
// ---------------------------------------------------------------------------
__global__ __launch_bounds__(256) void csr_count(
    const int* __restrict__ ei, int* __restrict__ deg, int E)
{
    const int e = blockIdx.x * 256 + threadIdx.x;
    if (e < E) atomicAdd(&deg[ei[E + e]], 1);
}

__global__ __launch_bounds__(256) void csr_scanA(
    const int* __restrict__ deg, int* __restrict__ row_start,
    int* __restrict__ bsum, int N)
{
    __shared__ int sd[256];
    const int t    = threadIdx.x;
    const int base = blockIdx.x * SCAN_CHUNK + t * 4;

    int d[4];
    #pragma unroll
    for (int j = 0; j < 4; ++j) d[j] = (base + j < N) ? deg[base + j] : 0;
    const int tsum = d[0] + d[1] + d[2] + d[3];

    sd[t] = tsum;
    __syncthreads();
    for (int off = 1; off < 256; off <<= 1) {
        const int v = (t >= off) ? sd[t - off] : 0;
        __syncthreads();
        sd[t] += v;
        __syncthreads();
    }
    int run = sd[t] - tsum;
    #pragma unroll
    for (int j = 0; j < 4; ++j) {
        if (base + j < N) row_start[base + j] = run;
        run += d[j];
    }
    if (t == 255) bsum[blockIdx.x] = sd[255];
}

// wave-parallel exclusive scan of block sums (NB <= 64) + row_start[N] = E
__global__ void csr_scanB(int* __restrict__ bsum, int* __restrict__ row_start,
                          int NB, int N, int E)
{
    const int lane = threadIdx.x & 63;
    int v = (lane < NB) ? bsum[lane] : 0;
    int x = v;
    #pragma unroll
    for (int off = 1; off < 64; off <<= 1) {
        const int u = __shfl(x, lane - off);
        if (lane >= off) x += u;
    }
    if (lane < NB) bsum[lane] = x - v;   // exclusive
    if (lane == 0) row_start[N] = E;
}

__global__ __launch_bounds__(256) void csr_scanC(
    int* __restrict__ row_start, int* __restrict__ cursor,
    const int* __restrict__ bsum, int N)
{
    const int i = blockIdx.x * 256 + threadIdx.x;
    if (i < N) {
        const int v = row_start[i] + bsum[i / SCAN_CHUNK];
        row_start[i] = v;
        cursor[i] = v;
    }
}

__global__ __launch_bounds__(256) void csr_fill(
    const int* __restrict__ ei, int* __restrict__ cursor,
    int* __restrict__ col, int E)
{
    const int e = blockIdx.x * 256 + threadIdx.x;
    if (e < E) {
        const int s = ei[e];
        const int d = ei[E + e];
        const int p = atomicAdd(&cursor[d], 1);
        col[p] = s;
    }
}

// ---------------------------------------------------------------------------
// Kernel 2: standalone gather. One TRUE wave64 per node (4 nodes / 256-thr
// block), no LDS, minimal VGPR -> max occupancy & TLP to hide the
// col[e] -> y_relw[src] pointer chase.  h = relu(agg + sum) packed bf16.
// ---------------------------------------------------------------------------
__global__ __launch_bounds__(256) void graphmae_gather(
    const int* __restrict__ row_start, const int* __restrict__ col,
    const unsigned int* __restrict__ y_relw, const float* __restrict__ agg,
    unsigned int* __restrict__ hw, int N)
{
    const int n = blockIdx.x * 4 + (threadIdx.x >> 6);
    if (n >= N) return;
    const int lane = threadIdx.x & 63;
    const int es   = lane >> 4;   // edge slot 0..3
    const int cl   = lane & 15;   // col group: floats cl*4 .. cl*4+3

    const int beg = row_start[n];     // wave-uniform -> scalar loads
    const int end = row_start[n + 1];

    // independent init-read issued before the chase so it overlaps
    float4 a0 = make_float4(0.f, 0.f, 0.f, 0.f);
    if (es == 0) a0 = *(const float4*)(agg + (size_t)n * HID + cl * 4);

    float4 acc = make_float4(0.f, 0.f, 0.f, 0.f);
    for (int e = beg + es; e < end; e += 4) {
        const int s = col[e];
        const uint2 v = *(const uint2*)(y_relw + (size_t)s * 32 + cl * 2);
        acc.x += __uint_as_float(v.x << 16);
        acc.y += __uint_as_float(v.x & 0xffff0000u);
        acc.z += __uint_as_float(v.y << 16);
        acc.w += __uint_as_float(v.y & 0xffff0000u);
    }
    // reduce the 4 edge slots (lane bits 4,5)
    acc.x += __shfl_xor(acc.x, 16); acc.y += __shfl_xor(acc.y, 16);
    acc.z += __shfl_xor(acc.z, 16); acc.w += __shfl_xor(acc.w, 16);
    acc.x += __shfl_xor(acc.x, 32); acc.y += __shfl_xor(acc.y, 32);
    acc.z += __shfl_xor(acc.z, 32); acc.w += __shfl_xor(acc.w, 32);

    if (es == 0) {
        const float hx = fmaxf(a0.x + acc.x, 0.f);
        const float hy = fmaxf(a0.y + acc.y, 0.f);
        const float hz = fmaxf(a0.z + acc.z, 0.f);
        const float hwv = fmaxf(a0.w + acc.w, 0.f);
        *(uint2*)(hw + (size_t)n * 32 + cl * 2) =
            make_uint2(bf16pair(hx, hy), bf16pair(hz, hwv));
    }
}

// ---------------------------------------------------------------------------
// Kernel 3: decoder.  out[n][c] = sum_k h[n][k] * W_dec[k][c] + b_dec[c]
// h arrives packed bf16 (already relu'd); unpack to f32 LDS tile.
// ---------------------------------------------------------------------------
__global__ __launch_bounds__(256) void graphmae_decode(
    const unsigned int* __restrict__ hw, const float* __restrict__ W_dec,
    const float* __restrict__ b_dec, float* __restrict__ out, int N)
{
    __shared__ float wd[64 * 128];   // W_dec
    __shared__ float hs[32 * 68];    // h tile, padded

    const int t  = threadIdx.x;
    const int n0 = blockIdx.x * 32;

    #pragma unroll
    for (int p = 0; p < 8; ++p) {
        const int idx = t + p * 256;
        *(float4*)(wd + idx * 4) = *(const float4*)(W_dec + (size_t)idx * 4);
    }
    // stage h: 32 rows x 32 words; each thread unpacks one uint2 x2
    #pragma unroll
    for (int p = 0; p < 2; ++p) {
        const int idx = t + p * 256;      // uint2 index 0..511
        const int row = idx >> 4;         // 0..31
        const int cw  = (idx & 15) * 2;   // word offset 0..30
        const int n   = n0 + row;
        uint2 v = make_uint2(0u, 0u);
        if (n < N) v = *(const uint2*)(hw + (size_t)n * 32 + cw);
        float* d = hs + row * 68 + cw * 2;
        d[0] = __uint_as_float(v.x << 16);
        d[1] = __uint_as_float(v.x & 0xffff0000u);
        d[2] = __uint_as_float(v.y << 16);
        d[3] = __uint_as_float(v.y & 0xffff0000u);
    }
    __syncthreads();

    const int tc = t & 31;
    const int tr = t >> 5;

    float acc[4][4];
    #pragma unroll
    for (int i = 0; i < 4; ++i)
        #pragma unroll
        for (int j = 0; j < 4; ++j) acc[i][j] = 0.f;

    const int c0 = tc * 4;
    #pragma unroll 2
    for (int k = 0; k < 64; k += 4) {
        float4 w0 = *(const float4*)(wd + (k + 0) * 128 + c0);
        float4 w1 = *(const float4*)(wd + (k + 1) * 128 + c0);
        float4 w2 = *(const float4*)(wd + (k + 2) * 128 + c0);
        float4 w3 = *(const float4*)(wd + (k + 3) * 128 + c0);
        const float* w0f = (const float*)&w0;
        const float* w1f = (const float*)&w1;
        const float* w2f = (const float*)&w2;
        const float* w3f = (const float*)&w3;
        #pragma unroll
        for (int i = 0; i < 4; ++i) {
            const float4 hv = *(const float4*)(hs + (tr * 4 + i) * 68 + k);
            const float* hf = (const float*)&hv;
            #pragma unroll
            for (int j = 0; j < 4; ++j) {
                acc[i][j] += hf[0] * w0f[j];
                acc[i][j] += hf[1] * w1f[j];
                acc[i][j] += hf[2] * w2f[j];
                acc[i][j] += hf[3] * w3f[j];
            }
        }
    }

    const float4 bd = *(const float4*)(b_dec + c0);
    #pragma unroll
    for (int i = 0; i < 4; ++i) {
        const int n = n0 + tr * 4 + i;
        if (n < N)
            *(float4*)(out + (size_t)n * IN_CH + c0) =
                make_float4(acc[i][0] + bd.x, acc[i][1] + bd.y,
                            acc[i][2] + bd.z, acc[i][3] + bd.w);
    }
}

// ---------------------------------------------------------------------------
extern "C" void kernel_launch(void* const* d_in, const int* in_sizes, int n_in,
                              void* d_out, int out_size, void* d_ws, size_t ws_size,
                              hipStream_t stream)
{
    const float* x      = (const float*)d_in[0];
    const int*   ei     = (const int*)  d_in[1];   // [2][E] int32
    const float* W_rel  = (const float*)d_in[2];
    const float* b_rel  = (const float*)d_in[3];
    const float* W_root = (const float*)d_in[4];
    const float* W_dec  = (const float*)d_in[5];
    const float* b_dec  = (const float*)d_in[6];
    float* out = (float*)d_out;

    const int N = in_sizes[0] / IN_CH;
    const int E = in_sizes[1] / 2;

    unsigned int* y_relw = (unsigned int*)d_ws;               // [N][32] (bf16x2)
    float* agg       = (float*)(y_relw + (size_t)N * 32);     // [N][64] f32
    unsigned int* hw = (unsigned int*)(agg + (size_t)N * HID);// [N][32] (bf16x2)
    int*   row_start = (int*)(hw + (size_t)N * 32);           // [N+1]
    int*   cursor    = row_start + (N + 1);                   // [N]
    int*   deg       = cursor + N;                            // [N]
    int*   col       = deg + N;                               // [E]
    int*   bsum      = col + E;                               // [NB]

    const int nblk = (N + 31) / 32;
    const int nthr = (N + 255) / 256;
    const int ethr = (E + 255) / 256;
    const int NB   = (N + SCAN_CHUNK - 1) / SCAN_CHUNK;

    graphmae_encode<<<nblk, 256, 0, stream>>>(x, W_rel, b_rel, W_root,
                                              y_relw, agg, deg, N);
    csr_count<<<ethr, 256, 0, stream>>>(ei, deg, E);
    csr_scanA<<<NB,   256, 0, stream>>>(deg, row_start, bsum, N);
    csr_scanB<<<1,     64, 0, stream>>>(bsum, row_start, NB, N, E);
    csr_scanC<<<nthr, 256, 0, stream>>>(row_start, cursor, bsum, N);
    csr_fill <<<ethr, 256, 0, stream>>>(ei, cursor, col, E);

    const int gblk = (N + 3) / 4;   // one wave64 per node
    graphmae_gather<<<gblk, 256, 0, stream>>>(row_start, col, y_relw, agg, hw, N);

    graphmae_decode<<<nblk, 256, 0, stream>>>(hw, W_dec, b_dec, out, N);
}

// Round 6
// 143.475 us; speedup vs baseline: 1.2418x; 1.0033x over previous
//
#include <hip/hip_runtime.h>

#define IN_CH 128
#define HID 64

typedef short v8s __attribute__((ext_vector_type(8)));   // 8 bf16 (4 VGPRs)
typedef float v4f __attribute__((ext_vector_type(4)));   // 4 f32 acc
typedef unsigned long long ull;

// branch-free f32 -> bf16 (round-to-nearest-even), pure uint math
__device__ __forceinline__ unsigned int bf16pair(float a, float b) {
    unsigned int ua = __float_as_uint(a);
    unsigned int ub = __float_as_uint(b);
    ua = (ua + 0x7fffu + ((ua >> 16) & 1u)) >> 16;
    ub = (ub + 0x7fffu + ((ub >> 16) & 1u)) & 0xffff0000u;
    return ua | ub;
}
__device__ __forceinline__ unsigned short bf16of(float a) {
    unsigned int ua = __float_as_uint(a);
    return (unsigned short)((ua + 0x7fffu + ((ua >> 16) & 1u)) >> 16);
}

// ---------------------------------------------------------------------------
// Kernel 1: MFMA encoder (+ deg zeroing).
//   y16[n][c] = bf16( x[n][:] @ W_rel[:][c] )          c in 0..63
//   agg[n][c] = x[n][:] @ W_root[:][c] + b_rel[c]      f32 gather-init
// Tile: 64 nodes x 128 cols (W_rel | W_root), 4 waves, each wave owns a
// 16-node tile x 8 col-tiles x (K=128 -> 4 MFMA steps) = 32 MFMAs.
// LDS rows padded +8 bf16 -> row stride 272B -> bank rotation 4 (2-way free).
// ---------------------------------------------------------------------------
__global__ __launch_bounds__(256) void graphmae_encode(
    const float* __restrict__ x, const float* __restrict__ W_rel,
    const float* __restrict__ b_rel, const float* __restrict__ W_root,
    unsigned short* __restrict__ y16, float* __restrict__ agg,
    int* __restrict__ deg, int N)
{
    __shared__ unsigned short As[64][136];    // x tile, bf16
    __shared__ unsigned short Bs[128][136];   // [W_rel|W_root]^T, bf16: [col][k]

    const int t  = threadIdx.x;
    const int n0 = blockIdx.x * 64;

    { const int z = blockIdx.x * 256 + t; if (z < N) deg[z] = 0; }

    // ---- stage x -> As (bf16): 4 threads/row, 8 float4 each ----
    {
        const int r = t >> 2, q = t & 3;
        const int n = n0 + r;
        unsigned short* ap = &As[r][q * 32];
        if (n < N) {
            const float* xp = x + (size_t)n * IN_CH + q * 32;
            #pragma unroll
            for (int j = 0; j < 8; ++j) {
                const float4 v = *(const float4*)(xp + j * 4);
                *(uint2*)(ap + j * 4) =
                    make_uint2(bf16pair(v.x, v.y), bf16pair(v.z, v.w));
            }
        } else {
            #pragma unroll
            for (int j = 0; j < 8; ++j) *(uint2*)(ap + j * 4) = make_uint2(0u, 0u);
        }
    }
    // ---- stage weights -> Bs transposed (bf16): coalesced f32 reads ----
    #pragma unroll
    for (int p = 0; p < 16; ++p) {
        const int idx = t + p * 256;        // float4 id 0..4095
        const int k   = idx >> 5;           // 0..127
        const int c4  = (idx & 31) * 4;     // 0..124
        float4 v;
        if (c4 < HID) v = *(const float4*)(W_rel  + (size_t)k * HID + c4);
        else          v = *(const float4*)(W_root + (size_t)k * HID + (c4 - HID));
        Bs[c4 + 0][k] = bf16of(v.x);
        Bs[c4 + 1][k] = bf16of(v.y);
        Bs[c4 + 2][k] = bf16of(v.z);
        Bs[c4 + 3][k] = bf16of(v.w);
    }
    __syncthreads();

    const int w    = t >> 6;       // wave -> node-tile (rows 16w..16w+15)
    const int lane = t & 63;
    const int mr   = lane & 15;
    const int kg   = lane >> 4;    // k-group 0..3

    v8s afrag[4];
    #pragma unroll
    for (int ks = 0; ks < 4; ++ks)
        afrag[ks] = *(const v8s*)(&As[w * 16 + mr][ks * 32 + kg * 8]);

    const int rbase = n0 + w * 16 + kg * 4;   // C/D: row = kg*4 + reg
    #pragma unroll
    for (int ct = 0; ct < 8; ++ct) {
        v4f acc = {0.f, 0.f, 0.f, 0.f};
        #pragma unroll
        for (int ks = 0; ks < 4; ++ks) {
            const v8s b = *(const v8s*)(&Bs[ct * 16 + mr][ks * 32 + kg * 8]);
            acc = __builtin_amdgcn_mfma_f32_16x16x32_bf16(afrag[ks], b, acc, 0, 0, 0);
        }
        const int c = ct * 16 + mr;           // C/D: col = lane&15
        if (ct < 4) {
            #pragma unroll
            for (int r = 0; r < 4; ++r) {
                const int n = rbase + r;
                if (n < N) y16[(size_t)n * HID + c] = bf16of(acc[r]);
            }
        } else {
            const float br = b_rel[c - HID];
            #pragma unroll
            for (int r = 0; r < 4; ++r) {
                const int n = rbase + r;
                if (n < N) agg[(size_t)n * HID + (c - HID)] = acc[r] + br;
            }
        }
    }
}

// ---------------------------------------------------------------------------
// CSR build: count (+ zero scan tiles) -> lookback scan -> fill
// ---------------------------------------------------------------------------
__global__ __launch_bounds__(256) void csr_count(
    const int* __restrict__ ei, int* __restrict__ deg,
    ull* __restrict__ tpack, int E)
{
    if (blockIdx.x == 0 && threadIdx.x < 64) tpack[threadIdx.x] = 0ull;
    const int e = blockIdx.x * 256 + threadIdx.x;
    if (e < E) atomicAdd(&deg[ei[E + e]], 1);
}

// single-pass decoupled-lookback exclusive scan; writes row_start AND cursor.
// tpack[b] = (status<<32)|value; status: 1=aggregate, 2=inclusive prefix.
__global__ __launch_bounds__(256) void csr_scan(
    const int* __restrict__ deg, int* __restrict__ row_start,
    int* __restrict__ cursor, ull* __restrict__ tpack, int N, int E)
{
    __shared__ int sd[256];
    __shared__ int s_prev;
    const int b = blockIdx.x, t = threadIdx.x;
    const int base = b * 1024 + t * 4;

    int d[4];
    #pragma unroll
    for (int j = 0; j < 4; ++j) d[j] = (base + j < N) ? deg[base + j] : 0;
    const int tsum = d[0] + d[1] + d[2] + d[3];

    sd[t] = tsum;
    __syncthreads();
    for (int off = 1; off < 256; off <<= 1) {
        const int v = (t >= off) ? sd[t - off] : 0;
        __syncthreads();
        sd[t] += v;
        __syncthreads();
    }
    const int total = sd[255];

    if (t == 0) {
        if (b == 0) {
            __hip_atomic_store(&tpack[0], (2ull << 32) | (unsigned)total,
                               __ATOMIC_RELEASE, __HIP_MEMORY_SCOPE_AGENT);
            s_prev = 0;
            row_start[N] = E;
        } else {
            __hip_atomic_store(&tpack[b], (1ull << 32) | (unsigned)total,
                               __ATOMIC_RELEASE, __HIP_MEMORY_SCOPE_AGENT);
            int prev = 0;
            int i = b - 1;
            while (true) {
                const ull p = __hip_atomic_load(&tpack[i], __ATOMIC_ACQUIRE,
                                                __HIP_MEMORY_SCOPE_AGENT);
                const unsigned st = (unsigned)(p >> 32);
                if (st == 2u) { prev += (int)(unsigned)p; break; }
                if (st == 1u) { prev += (int)(unsigned)p; --i; }
            }
            __hip_atomic_store(&tpack[b], (2ull << 32) | (unsigned)(prev + total),
                               __ATOMIC_RELEASE, __HIP_MEMORY_SCOPE_AGENT);
            s_prev = prev;
        }
    }
    __syncthreads();

    int run = s_prev + sd[t] - tsum;
    #pragma unroll
    for (int j = 0; j < 4; ++j) {
        if (base + j < N) { row_start[base + j] = run; cursor[base + j] = run; }
        run += d[j];
    }
}

__global__ __launch_bounds__(256) void csr_fill(
    const int* __restrict__ ei, int* __restrict__ cursor,
    int* __restrict__ col, int E)
{
    const int e = blockIdx.x * 256 + threadIdx.x;
    if (e < E) {
        const int s = ei[e];
        const int d = ei[E + e];
        const int p = atomicAdd(&cursor[d], 1);
        col[p] = s;
    }
}

// ---------------------------------------------------------------------------
// Kernel 2: standalone gather (unchanged from round 5 — it works).
// One TRUE wave64 per node; h = relu(agg + sum y_rel[src]) packed bf16.
// ---------------------------------------------------------------------------
__global__ __launch_bounds__(256) void graphmae_gather(
    const int* __restrict__ row_start, const int* __restrict__ col,
    const unsigned int* __restrict__ y_relw, const float* __restrict__ agg,
    unsigned int* __restrict__ hw, int N)
{
    const int n = blockIdx.x * 4 + (threadIdx.x >> 6);
    if (n >= N) return;
    const int lane = threadIdx.x & 63;
    const int es   = lane >> 4;
    const int cl   = lane & 15;

    const int beg = row_start[n];
    const int end = row_start[n + 1];

    float4 a0 = make_float4(0.f, 0.f, 0.f, 0.f);
    if (es == 0) a0 = *(const float4*)(agg + (size_t)n * HID + cl * 4);

    float4 acc = make_float4(0.f, 0.f, 0.f, 0.f);
    for (int e = beg + es; e < end; e += 4) {
        const int s = col[e];
        const uint2 v = *(const uint2*)(y_relw + (size_t)s * 32 + cl * 2);
        acc.x += __uint_as_float(v.x << 16);
        acc.y += __uint_as_float(v.x & 0xffff0000u);
        acc.z += __uint_as_float(v.y << 16);
        acc.w += __uint_as_float(v.y & 0xffff0000u);
    }
    acc.x += __shfl_xor(acc.x, 16); acc.y += __shfl_xor(acc.y, 16);
    acc.z += __shfl_xor(acc.z, 16); acc.w += __shfl_xor(acc.w, 16);
    acc.x += __shfl_xor(acc.x, 32); acc.y += __shfl_xor(acc.y, 32);
    acc.z += __shfl_xor(acc.z, 32); acc.w += __shfl_xor(acc.w, 32);

    if (es == 0) {
        const float hx = fmaxf(a0.x + acc.x, 0.f);
        const float hy = fmaxf(a0.y + acc.y, 0.f);
        const float hz = fmaxf(a0.z + acc.z, 0.f);
        const float hv = fmaxf(a0.w + acc.w, 0.f);
        *(uint2*)(hw + (size_t)n * 32 + cl * 2) =
            make_uint2(bf16pair(hx, hy), bf16pair(hz, hv));
    }
}

// ---------------------------------------------------------------------------
// Kernel 3: MFMA decoder. h (bf16 packed) @ W_dec (-> bf16) + b_dec, f32 out.
// Tile 64 nodes x 128 cols, K=64 -> 2 MFMA steps; LDS rows padded +8 bf16.
// ---------------------------------------------------------------------------
__global__ __launch_bounds__(256) void graphmae_decode(
    const unsigned int* __restrict__ hw, const float* __restrict__ W_dec,
    const float* __restrict__ b_dec, float* __restrict__ out, int N)
{
    __shared__ unsigned short As[64][72];    // h tile bf16
    __shared__ unsigned short Bs[128][72];   // W_dec^T bf16: [col][k]

    const int t  = threadIdx.x;
    const int n0 = blockIdx.x * 64;

    // stage h words: 4 threads/row, 8 words (16 bf16) each
    {
        const int r = t >> 2, q = t & 3;
        const int n = n0 + r;
        unsigned short* ap = &As[r][q * 16];
        if (n < N) {
            const unsigned int* hp = hw + (size_t)n * 32 + q * 8;
            #pragma unroll
            for (int j = 0; j < 4; ++j)
                *(uint2*)(ap + j * 4) = *(const uint2*)(hp + j * 2);
        } else {
            #pragma unroll
            for (int j = 0; j < 4; ++j) *(uint2*)(ap + j * 4) = make_uint2(0u, 0u);
        }
    }
    // stage W_dec -> Bs transposed bf16
    #pragma unroll
    for (int p = 0; p < 8; ++p) {
        const int idx = t + p * 256;       // float4 id 0..2047
        const int k   = idx >> 5;          // 0..63
        const int c4  = (idx & 31) * 4;    // 0..124
        const float4 v = *(const float4*)(W_dec + (size_t)k * IN_CH + c4);
        Bs[c4 + 0][k] = bf16of(v.x);
        Bs[c4 + 1][k] = bf16of(v.y);
        Bs[c4 + 2][k] = bf16of(v.z);
        Bs[c4 + 3][k] = bf16of(v.w);
    }
    __syncthreads();

    const int w    = t >> 6;
    const int lane = t & 63;
    const int mr   = lane & 15;
    const int kg   = lane >> 4;

    v8s afrag[2];
    #pragma unroll
    for (int ks = 0; ks < 2; ++ks)
        afrag[ks] = *(const v8s*)(&As[w * 16 + mr][ks * 32 + kg * 8]);

    const int rbase = n0 + w * 16 + kg * 4;
    #pragma unroll
    for (int ct = 0; ct < 8; ++ct) {
        v4f acc = {0.f, 0.f, 0.f, 0.f};
        #pragma unroll
        for (int ks = 0; ks < 2; ++ks) {
            const v8s b = *(const v8s*)(&Bs[ct * 16 + mr][ks * 32 + kg * 8]);
            acc = __builtin_amdgcn_mfma_f32_16x16x32_bf16(afrag[ks], b, acc, 0, 0, 0);
        }
        const int c  = ct * 16 + mr;
        const float bd = b_dec[c];
        #pragma unroll
        for (int r = 0; r < 4; ++r) {
            const int n = rbase + r;
            if (n < N) out[(size_t)n * IN_CH + c] = acc[r] + bd;
        }
    }
}

// ---------------------------------------------------------------------------
extern "C" void kernel_launch(void* const* d_in, const int* in_sizes, int n_in,
                              void* d_out, int out_size, void* d_ws, size_t ws_size,
                              hipStream_t stream)
{
    const float* x      = (const float*)d_in[0];
    const int*   ei     = (const int*)  d_in[1];   // [2][E] int32
    const float* W_rel  = (const float*)d_in[2];
    const float* b_rel  = (const float*)d_in[3];
    const float* W_root = (const float*)d_in[4];
    const float* W_dec  = (const float*)d_in[5];
    const float* b_dec  = (const float*)d_in[6];
    float* out = (float*)d_out;

    const int N = in_sizes[0] / IN_CH;
    const int E = in_sizes[1] / 2;

    unsigned short* y16 = (unsigned short*)d_ws;                  // [N][64] bf16
    float*        agg   = (float*)(y16 + (size_t)N * HID);        // [N][64] f32
    unsigned int* hwv   = (unsigned int*)(agg + (size_t)N * HID); // [N][32] bf16x2
    int* row_start = (int*)(hwv + (size_t)N * 32);                // [N+1]
    int* cursor    = row_start + (N + 1);                         // [N]
    int* deg       = cursor + N;                                  // [N]
    int* col       = deg + N;                                     // [E]
    uintptr_t pt = (uintptr_t)(col + E);
    pt = (pt + 7) & ~(uintptr_t)7;
    ull* tpack = (ull*)pt;                                        // [64]

    const int nblk64 = (N + 63) / 64;
    const int ethr   = (E + 255) / 256;
    const int NB     = (N + 1023) / 1024;

    graphmae_encode<<<nblk64, 256, 0, stream>>>(x, W_rel, b_rel, W_root,
                                                y16, agg, deg, N);
    csr_count<<<ethr, 256, 0, stream>>>(ei, deg, tpack, E);
    csr_scan <<<NB,   256, 0, stream>>>(deg, row_start, cursor, tpack, N, E);
    csr_fill <<<ethr, 256, 0, stream>>>(ei, cursor, col, E);

    const int gblk = (N + 3) / 4;
    graphmae_gather<<<gblk, 256, 0, stream>>>(row_start, col,
                                              (const unsigned int*)y16, agg, hwv, N);
    graphmae_decode<<<nblk64, 256, 0, stream>>>(hwv, W_dec, b_dec, out, N);
}

// Round 7
// 142.991 us; speedup vs baseline: 1.2460x; 1.0034x over previous
//
#include <hip/hip_runtime.h>

#define IN_CH 128
#define HID 64

typedef short v8s __attribute__((ext_vector_type(8)));   // 8 bf16 (4 VGPRs)
typedef float v4f __attribute__((ext_vector_type(4)));   // 4 f32 acc

// branch-free f32 -> bf16 (round-to-nearest-even), pure uint math
__device__ __forceinline__ unsigned int bf16pair(float a, float b) {
    unsigned int ua = __float_as_uint(a);
    unsigned int ub = __float_as_uint(b);
    ua = (ua + 0x7fffu + ((ua >> 16) & 1u)) >> 16;          // elem0 -> low 16
    ub = (ub + 0x7fffu + ((ub >> 16) & 1u)) & 0xffff0000u;  // elem1 -> high 16
    return ua | ub;
}
__device__ __forceinline__ unsigned short bf16of(float a) {
    unsigned int ua = __float_as_uint(a);
    return (unsigned short)((ua + 0x7fffu + ((ua >> 16) & 1u)) >> 16);
}

// ---------------------------------------------------------------------------
// Kernel 1: fused encoder GEMMs (VALU f32 — the proven round-5 version)
//   y16[n][c] = bf16( x[n][:] @ W_rel[:][c] )       packed 2/word
//   agg[n][c] = x[n][:] @ W_root[:][c] + b_rel[c]   f32 gather-init
// + head4 init to -1 (782*256 threads >= 4N).
// ---------------------------------------------------------------------------
__global__ __launch_bounds__(256) void graphmae_encode(
    const float* __restrict__ x, const float* __restrict__ W_rel,
    const float* __restrict__ b_rel, const float* __restrict__ W_root,
    unsigned int* __restrict__ y_relw, float* __restrict__ agg,
    int* __restrict__ head4, int N)
{
    __shared__ float lw[64 * 128];   // k-half of [W_rel | W_root]
    __shared__ float xs[32 * 132];   // 32 x-rows, padded

    const int t  = threadIdx.x;
    const int tc = t & 31;
    const int tr = t >> 5;
    const int n0 = blockIdx.x * 32;

    // fold in: init the 4-sublist heads
    {
        const int z = blockIdx.x * 256 + t;
        if (z < 4 * N) head4[z] = -1;
    }

    #pragma unroll
    for (int p = 0; p < 4; ++p) {
        const int row = tr + p * 8;
        const int n   = n0 + row;
        float4 v = make_float4(0.f, 0.f, 0.f, 0.f);
        if (n < N) v = *(const float4*)(x + (size_t)n * IN_CH + tc * 4);
        *(float4*)(xs + row * 132 + tc * 4) = v;
    }

    float acc[4][4];
    #pragma unroll
    for (int i = 0; i < 4; ++i)
        #pragma unroll
        for (int j = 0; j < 4; ++j) acc[i][j] = 0.f;

    for (int kh = 0; kh < 2; ++kh) {
        __syncthreads();
        #pragma unroll
        for (int p = 0; p < 8; ++p) {
            const int idx  = t + p * 256;
            const int krow = idx >> 5;
            const int col4 = (idx & 31) * 4;
            float4 v;
            if (col4 < HID)
                v = *(const float4*)(W_rel  + (size_t)(kh * 64 + krow) * HID + col4);
            else
                v = *(const float4*)(W_root + (size_t)(kh * 64 + krow) * HID + (col4 - HID));
            *(float4*)(lw + idx * 4) = v;
        }
        __syncthreads();

        #pragma unroll 2
        for (int k = 0; k < 64; k += 4) {
            float4 w0 = *(const float4*)(lw + (k + 0) * 128 + tc * 4);
            float4 w1 = *(const float4*)(lw + (k + 1) * 128 + tc * 4);
            float4 w2 = *(const float4*)(lw + (k + 2) * 128 + tc * 4);
            float4 w3 = *(const float4*)(lw + (k + 3) * 128 + tc * 4);
            const float* w0f = (const float*)&w0;
            const float* w1f = (const float*)&w1;
            const float* w2f = (const float*)&w2;
            const float* w3f = (const float*)&w3;
            #pragma unroll
            for (int i = 0; i < 4; ++i) {
                const float4 xv = *(const float4*)(xs + (tr * 4 + i) * 132 + kh * 64 + k);
                const float* xf = (const float*)&xv;
                #pragma unroll
                for (int j = 0; j < 4; ++j) {
                    acc[i][j] += xf[0] * w0f[j];
                    acc[i][j] += xf[1] * w1f[j];
                    acc[i][j] += xf[2] * w2f[j];
                    acc[i][j] += xf[3] * w3f[j];
                }
            }
        }
    }

    const int c0 = (tc & 15) * 4;
    if (tc < 16) {
        #pragma unroll
        for (int i = 0; i < 4; ++i) {
            const int n = n0 + tr * 4 + i;
            if (n < N) {
                const unsigned int lo = bf16pair(acc[i][0], acc[i][1]);
                const unsigned int hi = bf16pair(acc[i][2], acc[i][3]);
                *(uint2*)(y_relw + (size_t)n * 32 + (c0 >> 1)) = make_uint2(lo, hi);
            }
        }
    } else {
        const float4 br = *(const float4*)(b_rel + c0);
        #pragma unroll
        for (int i = 0; i < 4; ++i) {
            const int n = n0 + tr * 4 + i;
            if (n < N)
                *(float4*)(agg + (size_t)n * HID + c0) =
                    make_float4(acc[i][0] + br.x, acc[i][1] + br.y,
                                acc[i][2] + br.z, acc[i][3] + br.w);
        }
    }
}

// ---------------------------------------------------------------------------
// Kernel 2: adjacency as 4 atomic linked lists per dst node.
// pairs[e] = {src, prev}; head4[d*4 + (e&3)] -> newest edge of sublist.
// pairs writes are coalesced (indexed by e); only the Exch is random.
// ---------------------------------------------------------------------------
__global__ __launch_bounds__(256) void csr_listfill(
    const int* __restrict__ ei, int* __restrict__ head4,
    uint2* __restrict__ pairs, int E)
{
    const int e = blockIdx.x * 256 + threadIdx.x;
    if (e < E) {
        const int s = ei[e];
        const int d = ei[E + e];
        const int prev = atomicExch(&head4[d * 4 + (e & 3)], e);
        pairs[e] = make_uint2((unsigned)s, (unsigned)prev);
    }
}

// ---------------------------------------------------------------------------
// Kernel 3: gather. One wave64 per node; lane owns one of the 64 h-columns.
// Walks the node's 4 chains interleaved (4-way ILP on the pointer chase);
// each pairs[e] load gives src AND next in one 8B access. Fully scalarized
// control (readfirstlane) -> s_load chains + SGPR-base payload loads.
// h = relu(agg + sum) stored bf16.
// ---------------------------------------------------------------------------
__global__ __launch_bounds__(256) void graphmae_gather(
    const int* __restrict__ head4, const uint2* __restrict__ pairs,
    const unsigned short* __restrict__ y16, const float* __restrict__ agg,
    unsigned short* __restrict__ h16, int N)
{
    const int n = blockIdx.x * 4 + (threadIdx.x >> 6);
    if (n >= N) return;
    const int lane = threadIdx.x & 63;

    const float a0 = agg[(size_t)n * HID + lane];   // issue early

    int e0 = __builtin_amdgcn_readfirstlane(head4[n * 4 + 0]);
    int e1 = __builtin_amdgcn_readfirstlane(head4[n * 4 + 1]);
    int e2 = __builtin_amdgcn_readfirstlane(head4[n * 4 + 2]);
    int e3 = __builtin_amdgcn_readfirstlane(head4[n * 4 + 3]);

    float acc = 0.f;
    while (e0 >= 0 || e1 >= 0 || e2 >= 0 || e3 >= 0) {
        unsigned int s0 = 0, s1 = 0, s2 = 0, s3 = 0;
        int f0 = -1, f1 = -1, f2 = -1, f3 = -1;
        const bool b0 = e0 >= 0, b1 = e1 >= 0, b2 = e2 >= 0, b3 = e3 >= 0;
        if (b0) { const uint2 p = pairs[e0];
                  s0 = __builtin_amdgcn_readfirstlane(p.x);
                  f0 = __builtin_amdgcn_readfirstlane((int)p.y); }
        if (b1) { const uint2 p = pairs[e1];
                  s1 = __builtin_amdgcn_readfirstlane(p.x);
                  f1 = __builtin_amdgcn_readfirstlane((int)p.y); }
        if (b2) { const uint2 p = pairs[e2];
                  s2 = __builtin_amdgcn_readfirstlane(p.x);
                  f2 = __builtin_amdgcn_readfirstlane((int)p.y); }
        if (b3) { const uint2 p = pairs[e3];
                  s3 = __builtin_amdgcn_readfirstlane(p.x);
                  f3 = __builtin_amdgcn_readfirstlane((int)p.y); }
        if (b0) acc += __uint_as_float((unsigned)y16[(size_t)s0 * HID + lane] << 16);
        if (b1) acc += __uint_as_float((unsigned)y16[(size_t)s1 * HID + lane] << 16);
        if (b2) acc += __uint_as_float((unsigned)y16[(size_t)s2 * HID + lane] << 16);
        if (b3) acc += __uint_as_float((unsigned)y16[(size_t)s3 * HID + lane] << 16);
        e0 = f0; e1 = f1; e2 = f2; e3 = f3;
    }

    h16[(size_t)n * HID + lane] = bf16of(fmaxf(a0 + acc, 0.f));
}

// ---------------------------------------------------------------------------
// Kernel 4: MFMA decoder (round-6 version). h (bf16) @ W_dec(->bf16) + b_dec.
// ---------------------------------------------------------------------------
__global__ __launch_bounds__(256) void graphmae_decode(
    const unsigned short* __restrict__ h16, const float* __restrict__ W_dec,
    const float* __restrict__ b_dec, float* __restrict__ out, int N)
{
    __shared__ unsigned short As[64][72];    // h tile bf16
    __shared__ unsigned short Bs[128][72];   // W_dec^T bf16: [col][k]

    const int t  = threadIdx.x;
    const int n0 = blockIdx.x * 64;

    {
        const int r = t >> 2, q = t & 3;
        const int n = n0 + r;
        unsigned short* ap = &As[r][q * 16];
        if (n < N) {
            const unsigned short* hp = h16 + (size_t)n * HID + q * 16;
            #pragma unroll
            for (int j = 0; j < 4; ++j)
                *(uint2*)(ap + j * 4) = *(const uint2*)(hp + j * 4);
        } else {
            #pragma unroll
            for (int j = 0; j < 4; ++j) *(uint2*)(ap + j * 4) = make_uint2(0u, 0u);
        }
    }
    #pragma unroll
    for (int p = 0; p < 8; ++p) {
        const int idx = t + p * 256;       // float4 id 0..2047
        const int k   = idx >> 5;          // 0..63
        const int c4  = (idx & 31) * 4;    // 0..124
        const float4 v = *(const float4*)(W_dec + (size_t)k * IN_CH + c4);
        Bs[c4 + 0][k] = bf16of(v.x);
        Bs[c4 + 1][k] = bf16of(v.y);
        Bs[c4 + 2][k] = bf16of(v.z);
        Bs[c4 + 3][k] = bf16of(v.w);
    }
    __syncthreads();

    const int w    = t >> 6;
    const int lane = t & 63;
    const int mr   = lane & 15;
    const int kg   = lane >> 4;

    v8s afrag[2];
    #pragma unroll
    for (int ks = 0; ks < 2; ++ks)
        afrag[ks] = *(const v8s*)(&As[w * 16 + mr][ks * 32 + kg * 8]);

    const int rbase = n0 + w * 16 + kg * 4;
    #pragma unroll
    for (int ct = 0; ct < 8; ++ct) {
        v4f acc = {0.f, 0.f, 0.f, 0.f};
        #pragma unroll
        for (int ks = 0; ks < 2; ++ks) {
            const v8s b = *(const v8s*)(&Bs[ct * 16 + mr][ks * 32 + kg * 8]);
            acc = __builtin_amdgcn_mfma_f32_16x16x32_bf16(afrag[ks], b, acc, 0, 0, 0);
        }
        const int c  = ct * 16 + mr;
        const float bd = b_dec[c];
        #pragma unroll
        for (int r = 0; r < 4; ++r) {
            const int n = rbase + r;
            if (n < N) out[(size_t)n * IN_CH + c] = acc[r] + bd;
        }
    }
}

// ---------------------------------------------------------------------------
extern "C" void kernel_launch(void* const* d_in, const int* in_sizes, int n_in,
                              void* d_out, int out_size, void* d_ws, size_t ws_size,
                              hipStream_t stream)
{
    const float* x      = (const float*)d_in[0];
    const int*   ei     = (const int*)  d_in[1];   // [2][E] int32
    const float* W_rel  = (const float*)d_in[2];
    const float* b_rel  = (const float*)d_in[3];
    const float* W_root = (const float*)d_in[4];
    const float* W_dec  = (const float*)d_in[5];
    const float* b_dec  = (const float*)d_in[6];
    float* out = (float*)d_out;

    const int N = in_sizes[0] / IN_CH;
    const int E = in_sizes[1] / 2;

    unsigned short* y16 = (unsigned short*)d_ws;                   // [N][64] bf16
    float* agg          = (float*)(y16 + (size_t)N * HID);         // [N][64] f32
    unsigned short* h16 = (unsigned short*)(agg + (size_t)N * HID);// [N][64] bf16
    int*   head4        = (int*)(h16 + (size_t)N * HID);           // [4N]
    uint2* pairs        = (uint2*)(head4 + (size_t)4 * N);         // [E] {src,prev}

    const int nblk32 = (N + 31) / 32;
    const int nblk64 = (N + 63) / 64;
    const int ethr   = (E + 255) / 256;

    graphmae_encode<<<nblk32, 256, 0, stream>>>(x, W_rel, b_rel, W_root,
                                                (unsigned int*)y16, agg, head4, N);
    csr_listfill<<<ethr, 256, 0, stream>>>(ei, head4, pairs, E);

    const int gblk = (N + 3) / 4;   // one wave64 per node
    graphmae_gather<<<gblk, 256, 0, stream>>>(head4, pairs, y16, agg, h16, N);

    graphmae_decode<<<nblk64, 256, 0, stream>>>(h16, W_dec, b_dec, out, N);
}